// Round 6
// baseline (371.295 us; speedup 1.0000x reference)
//
#include <hip/hip_runtime.h>
#include <hip/hip_bf16.h>

using bf16 = __hip_bfloat16;
typedef __bf16 bf16x8 __attribute__((ext_vector_type(8)));
typedef __bf16 bf16x4 __attribute__((ext_vector_type(4)));
typedef float f32x4 __attribute__((ext_vector_type(4)));
typedef float f32x16 __attribute__((ext_vector_type(16)));

#define BK 64

// ---------------------------------------------------------------------------
// Staging helper: 16B per lane via global_load_lds, wave-uniform LDS base.
// ---------------------------------------------------------------------------
__device__ __forceinline__ void stage16(const bf16* gsrc, bf16* lds_base)
{
    __builtin_amdgcn_global_load_lds(
        (__attribute__((address_space(1))) void*)(void*)gsrc,
        (__attribute__((address_space(3))) void*)(void*)lds_base,
        16, 0, 0);
}

// History:
// R5: chunk swizzle c^(row&7) killed 16x16-pattern conflicts (1.65e7->0).
// R11: 256^2 8-phase regressed (grid quantization + short K). Wrong regime.
// R12: 32x32x16 MFMA: fc1 67->62.6us; adds 5.5e6 conflict-cyc (4/read).
// R13: conflict is a 32-lane half-wave floor for b128 reads of 32x32
//      frags; row-XOR can't fix. ACCEPTED (~2-5us, partly hidden).
// R14: t2 de-atomicized (split-K partials), rt1 768 blocks. 281->261us.
//      Session clock noise band +-12%: don't chase <10% single-kernel deltas.
// R15: fc2 128^2 retile REGRESSED (384 blocks = 1.5 rounds, occ 13.8%,
//      70.5us) — R11's quantization trap again. Even-round grids win.
//      rt1 gw fusion also cost 16KB LDS/block. Total 319us. REVERTED.
// R16 (this round): fc2 back to 64x128/768 blocks; rt1 gw fusion kept but
//      sg[4096] ALIASES the dead sA/sB staging LDS (zero occupancy cost);
//      t2 4-way reduce+scale+cvt fused into t2_splitk via last-z-block
//      (per-x counter + threadfence + AGENT-scope partial loads).
//      Launches 8 -> 6 to test the ~9us/launch gap hypothesis cleanly.
// ---------------------------------------------------------------------------

// ---------------------------------------------------------------------------
// fc1: 128x128 tiled MFMA GEMM, 32x32x16 fragments.
// C = relu([A0|A1] @ [B0;B1]^T + bias), bf16 out. Block=256 (4 waves, 2x2,
// each wave 64x64 = 2x2 fragments of 32x32).
// C/D: col=lane&31, row=(reg&3)+8*(reg>>2)+4*(lane>>5)  [m74/m101 verified].
// ---------------------------------------------------------------------------
__global__ __launch_bounds__(256)
void gemm_bt(const bf16* __restrict__ A0, int lda0, int K0,
             const bf16* __restrict__ A1, int lda1, int K1,
             const bf16* __restrict__ B0, int ldb0,
             const bf16* __restrict__ B1, int ldb1,
             const float* __restrict__ bias,
             int relu,
             bf16* __restrict__ C, int ldc)
{
    __shared__ bf16 sA[128 * BK];
    __shared__ bf16 sB[128 * BK];

    const int t = threadIdx.x;
    const int w = t >> 6;
    const int l = t & 63;
    const int wm = w >> 1;
    const int wn = w & 1;
    const int r32 = l & 31;        // row within 32x32 fragment
    const int h   = l >> 5;        // k-half selector
    const int rowA0 = blockIdx.x * 128;
    const int rowB0 = blockIdx.y * 128;

    f32x16 acc[2][2];
#pragma unroll
    for (int i = 0; i < 2; ++i)
#pragma unroll
        for (int j = 0; j < 2; ++j)
#pragma unroll
            for (int e = 0; e < 16; ++e)
                acc[i][j][e] = 0.f;

    const int nK = (K0 + K1) >> 6;
    for (int kt = 0; kt < nK; ++kt) {
        const int k0 = kt << 6;
        const bf16 *Ap, *Bp;
        int la, lb, ks;
        if (k0 < K0) { Ap = A0; la = lda0; Bp = B0; lb = ldb0; ks = k0; }
        else         { Ap = A1; la = lda1; Bp = B1; lb = ldb1; ks = k0 - K0; }

        __syncthreads();
#pragma unroll
        for (int it = 0; it < 4; ++it) {
            const int L   = it * 256 + t;
            const int row = L >> 3;
            const int cb  = (L & 7) ^ (row & 7);   // swizzled source chunk
            stage16(Ap + (size_t)(rowA0 + row) * la + ks + cb * 8,
                    sA + (size_t)(it * 256 + (w << 6)) * 8);
            stage16(Bp + (size_t)(rowB0 + row) * lb + ks + cb * 8,
                    sB + (size_t)(it * 256 + (w << 6)) * 8);
        }
        __syncthreads();

#pragma unroll
        for (int s = 0; s < 4; ++s) {              // 4 x K=16 sub-steps
            bf16x8 aF[2], bF[2];
#pragma unroll
            for (int i = 0; i < 2; ++i) {
                const int row = wm * 64 + i * 32 + r32;
                const int c   = (s * 2 + h) ^ (row & 7);
                aF[i] = *(const bf16x8*)&sA[row * BK + c * 8];
            }
#pragma unroll
            for (int j = 0; j < 2; ++j) {
                const int row = wn * 64 + j * 32 + r32;
                const int c   = (s * 2 + h) ^ (row & 7);
                bF[j] = *(const bf16x8*)&sB[row * BK + c * 8];
            }
#pragma unroll
            for (int i = 0; i < 2; ++i)
#pragma unroll
                for (int j = 0; j < 2; ++j)
                    acc[i][j] = __builtin_amdgcn_mfma_f32_32x32x16_bf16(
                        aF[i], bF[j], acc[i][j], 0, 0, 0);
        }
    }

    // C/D layout: col = lane&31, row = (reg&3) + 8*(reg>>2) + 4*h
#pragma unroll
    for (int i = 0; i < 2; ++i)
#pragma unroll
        for (int j = 0; j < 2; ++j) {
            const int col = rowB0 + wn * 64 + j * 32 + r32;
            const float bc = bias ? bias[col] : 0.f;
#pragma unroll
            for (int reg = 0; reg < 16; ++reg) {
                const int row = rowA0 + wm * 64 + i * 32 +
                                (reg & 3) + 8 * (reg >> 2) + 4 * h;
                float v = acc[i][j][reg] + bc;
                if (relu) v = v > 0.f ? v : 0.f;
                C[(size_t)row * ldc + col] = __float2bfloat16(v);
            }
        }
}

// ---------------------------------------------------------------------------
// fc2: 64x128 tile, fp32 out, 32x32x16 fragments. Grid (128,6)=768 blocks
// = 3.0 even rounds (R16: restored from R4; the 128^2 variant was R15's
// quantization trap). 4 waves 1x4; each wave 64x32 = 2x1 frags of 32x32.
// ---------------------------------------------------------------------------
__global__ __launch_bounds__(256)
void gemm_bt64(const bf16* __restrict__ A0, int lda0, int K0,
               const bf16* __restrict__ A1, int lda1, int K1,
               const bf16* __restrict__ B0, int ldb0,
               const bf16* __restrict__ B1, int ldb1,
               const float* __restrict__ bias,
               float* __restrict__ Cf, int ldc)
{
    __shared__ bf16 sA[64 * BK];
    __shared__ bf16 sB[128 * BK];

    const int t = threadIdx.x;
    const int w = t >> 6;
    const int l = t & 63;
    const int wn = w;
    const int r32 = l & 31;
    const int h   = l >> 5;
    const int rowA0 = blockIdx.x * 64;
    const int rowB0 = blockIdx.y * 128;

    f32x16 acc[2];
#pragma unroll
    for (int i = 0; i < 2; ++i)
#pragma unroll
        for (int e = 0; e < 16; ++e)
            acc[i][e] = 0.f;

    const int nK = (K0 + K1) >> 6;
    for (int kt = 0; kt < nK; ++kt) {
        const int k0 = kt << 6;
        const bf16 *Ap, *Bp;
        int la, lb, ks;
        if (k0 < K0) { Ap = A0; la = lda0; Bp = B0; lb = ldb0; ks = k0; }
        else         { Ap = A1; la = lda1; Bp = B1; lb = ldb1; ks = k0 - K0; }

        __syncthreads();
#pragma unroll
        for (int it = 0; it < 2; ++it) {
            const int L   = it * 256 + t;
            const int row = L >> 3;
            const int cb  = (L & 7) ^ (row & 7);
            stage16(Ap + (size_t)(rowA0 + row) * la + ks + cb * 8,
                    sA + (size_t)(it * 256 + (w << 6)) * 8);
        }
#pragma unroll
        for (int it = 0; it < 4; ++it) {
            const int L   = it * 256 + t;
            const int row = L >> 3;
            const int cb  = (L & 7) ^ (row & 7);
            stage16(Bp + (size_t)(rowB0 + row) * lb + ks + cb * 8,
                    sB + (size_t)(it * 256 + (w << 6)) * 8);
        }
        __syncthreads();

#pragma unroll
        for (int s = 0; s < 4; ++s) {
            bf16x8 aF[2], bF;
#pragma unroll
            for (int i = 0; i < 2; ++i) {
                const int row = i * 32 + r32;
                const int c   = (s * 2 + h) ^ (row & 7);
                aF[i] = *(const bf16x8*)&sA[row * BK + c * 8];
            }
            {
                const int row = wn * 32 + r32;
                const int c   = (s * 2 + h) ^ (row & 7);
                bF = *(const bf16x8*)&sB[row * BK + c * 8];
            }
#pragma unroll
            for (int i = 0; i < 2; ++i)
                acc[i] = __builtin_amdgcn_mfma_f32_32x32x16_bf16(
                    aF[i], bF, acc[i], 0, 0, 0);
        }
    }

#pragma unroll
    for (int i = 0; i < 2; ++i) {
        const int col = rowB0 + wn * 32 + r32;
        const float bc = bias[col];
#pragma unroll
        for (int reg = 0; reg < 16; ++reg) {
            const int row = rowA0 + i * 32 + (reg & 3) + 8 * (reg >> 2) + 4 * h;
            Cf[(size_t)row * ldc + col] = acc[i][reg] + bc;
        }
    }
}

// ---------------------------------------------------------------------------
// Fused router + t1 GEMM + gw. 64x64 tiles, grid (128,6)=768 blocks.
//   y=0..3 (router): bias+relu+sum -> atomicAdd gsum; LAST router block
//          (atomic counter == 511) computes gw[16,128] from gsum, staged
//          into LDS that ALIASES the dead sA/sB staging buffer (R16:
//          zero occupancy cost; R15's separate sg[4096] cost 16KB/block).
//   y=4,5  (t1): raw fp32 x@SVH1^T -> t1acc (non-atomic).
// 4 waves 2x2; 16x16 frags, R5 swizzle (conflict-free).
// ---------------------------------------------------------------------------
__global__ __launch_bounds__(256)
void rt1_kernel(const bf16* __restrict__ A, int lda,
                const bf16* __restrict__ B, int ldb,
                const float* __restrict__ gate_b1,
                const bf16* __restrict__ gw2b,
                const float* __restrict__ gate_b2,
                float* __restrict__ gsum, int* __restrict__ cnt,
                float* __restrict__ gw, float* __restrict__ t1acc)
{
    __shared__ bf16 sAB[128 * BK];          // sA = [0,64*BK), sB = [64*BK,..)
    __shared__ int lastflag;
    bf16* sA = sAB;
    bf16* sB = sAB + 64 * BK;
    float* sg = (float*)sAB;                // aliases sA+sB (16KB), used
                                            // only after final __syncthreads

    const int t = threadIdx.x;
    const int w = t >> 6;
    const int l = t & 63;
    const int wm = w >> 1;
    const int wn = w & 1;
    const int r = l & 15;
    const int q = l >> 4;
    const int sw = r & 7;
    const int rowA0 = blockIdx.x * 64;
    const int rowB0 = blockIdx.y * 64;
    const int b = rowA0 >> 9;

    f32x4 acc[2][2];
#pragma unroll
    for (int i = 0; i < 2; ++i)
#pragma unroll
        for (int j = 0; j < 2; ++j)
            acc[i][j] = (f32x4){0.f, 0.f, 0.f, 0.f};

    for (int kt = 0; kt < 12; ++kt) {      // K = 768
        const int ks = kt << 6;

        __syncthreads();
#pragma unroll
        for (int it = 0; it < 2; ++it) {
            const int L   = it * 256 + t;
            const int row = L >> 3;
            const int cb  = (L & 7) ^ (row & 7);
            stage16(A + (size_t)(rowA0 + row) * lda + ks + cb * 8,
                    sA + (size_t)(it * 256 + (w << 6)) * 8);
            stage16(B + (size_t)(rowB0 + row) * ldb + ks + cb * 8,
                    sB + (size_t)(it * 256 + (w << 6)) * 8);
        }
        __syncthreads();

#pragma unroll
        for (int kk = 0; kk < 2; ++kk) {
            const int ch = ((kk * 4 + q) ^ sw) * 8;
            bf16x8 aF[2], bF[2];
#pragma unroll
            for (int i = 0; i < 2; ++i)
                aF[i] = *(const bf16x8*)&sA[(wm * 32 + i * 16 + r) * BK + ch];
#pragma unroll
            for (int j = 0; j < 2; ++j)
                bF[j] = *(const bf16x8*)&sB[(wn * 32 + j * 16 + r) * BK + ch];
#pragma unroll
            for (int i = 0; i < 2; ++i)
#pragma unroll
                for (int j = 0; j < 2; ++j)
                    acc[i][j] = __builtin_amdgcn_mfma_f32_16x16x32_bf16(
                        aF[i], bF[j], acc[i][j], 0, 0, 0);
        }
    }

    if (rowB0 < 256) {
        // router: relu + per-wave 32-row sum; waves atomically merge
#pragma unroll
        for (int j = 0; j < 2; ++j) {
            const int col = rowB0 + wn * 32 + j * 16 + r;
            const float bc = gate_b1[col];
            float s = 0.f;
#pragma unroll
            for (int i = 0; i < 2; ++i)
#pragma unroll
                for (int rr = 0; rr < 4; ++rr) {
                    const float v = acc[i][j][rr] + bc;
                    s += v > 0.f ? v : 0.f;
                }
            s += __shfl_xor(s, 16, 64);
            s += __shfl_xor(s, 32, 64);
            if (q == 0) atomicAdd(&gsum[b * 256 + col], s);
        }

        // last router block computes gw (fused gw_kernel)
        __threadfence();
        __syncthreads();                 // all threads past last sA/sB read
        if (t == 0) {
            const int old = atomicAdd(cnt, 1);
            lastflag = (old == 511);
        }
        __syncthreads();
        if (lastflag) {
            for (int i = t; i < 4096; i += 256)
                sg[i] = __hip_atomic_load(&gsum[i], __ATOMIC_RELAXED,
                                          __HIP_MEMORY_SCOPE_AGENT);
            __syncthreads();
            for (int o = t; o < 2048; o += 256) {
                const int bb = o >> 7, c = o & 127;
                const float* gs = &sg[bb * 256];
                const bf16x8* wrow = (const bf16x8*)&gw2b[c * 256];
                float s = 0.f;
                for (int j8 = 0; j8 < 32; ++j8) {
                    const bf16x8 v = wrow[j8];
#pragma unroll
                    for (int e = 0; e < 8; ++e)
                        s += gs[j8 * 8 + e] * (float)v[e];
                }
                gw[o] = gate_b2[c] + s * (1.0f / 512.0f);
            }
        }
    } else {
#pragma unroll
        for (int i = 0; i < 2; ++i)
#pragma unroll
            for (int j = 0; j < 2; ++j)
#pragma unroll
                for (int rr = 0; rr < 4; ++rr) {
                    const int row = rowA0 + wm * 32 + i * 16 + q * 4 + rr;
                    const int col = (rowB0 - 256) + wn * 32 + j * 16 + r;
                    t1acc[(size_t)row * 128 + col] = acc[i][j][rr];
                }
    }
}

// ---------------------------------------------------------------------------
// t2 split-K: grid (128, 1, 4), 64x128 tiles, 12 K-tiles per z, NON-ATOMIC
// per-z partial stores. R16: last-of-4 z-blocks per x (per-x counter)
// fuses the 4-way reduce + gw scale + bf16 cvt (removes scale_red4_cvt).
// Cross-XCD partials read with AGENT-scope atomic loads after threadfence.
// ---------------------------------------------------------------------------
__global__ __launch_bounds__(256)
void t2_splitk(const bf16* __restrict__ A, int lda,
               const bf16* __restrict__ B, int ldb,
               float* __restrict__ Cpart,
               const float* __restrict__ gw,
               bf16* __restrict__ t2buf,
               int* __restrict__ cnt2)
{
    __shared__ bf16 sA[64 * BK];
    __shared__ bf16 sB[128 * BK];
    __shared__ int lastz;

    const int t = threadIdx.x;
    const int w = t >> 6;
    const int l = t & 63;
    const int wn = w;
    const int r = l & 15;
    const int q = l >> 4;
    const int sw = r & 7;
    const int rowA0 = blockIdx.x * 64;
    const int z = blockIdx.z;
    const int ksbase = z * 12 * BK;
    float* Cz = Cpart + (size_t)z * 8192 * 128;

    f32x4 acc[4][2];
#pragma unroll
    for (int i = 0; i < 4; ++i)
#pragma unroll
        for (int j = 0; j < 2; ++j)
            acc[i][j] = (f32x4){0.f, 0.f, 0.f, 0.f};

    for (int kt = 0; kt < 12; ++kt) {
        const int ks = ksbase + kt * BK;

        __syncthreads();
#pragma unroll
        for (int it = 0; it < 2; ++it) {
            const int L   = it * 256 + t;
            const int row = L >> 3;
            const int cb  = (L & 7) ^ (row & 7);
            stage16(A + (size_t)(rowA0 + row) * lda + ks + cb * 8,
                    sA + (size_t)(it * 256 + (w << 6)) * 8);
        }
#pragma unroll
        for (int it = 0; it < 4; ++it) {
            const int L   = it * 256 + t;
            const int row = L >> 3;
            const int cb  = (L & 7) ^ (row & 7);
            stage16(B + (size_t)row * ldb + ks + cb * 8,
                    sB + (size_t)(it * 256 + (w << 6)) * 8);
        }
        __syncthreads();

#pragma unroll
        for (int kk = 0; kk < 2; ++kk) {
            const int ch = ((kk * 4 + q) ^ sw) * 8;
            bf16x8 aF[4], bF[2];
#pragma unroll
            for (int i = 0; i < 4; ++i)
                aF[i] = *(const bf16x8*)&sA[(i * 16 + r) * BK + ch];
#pragma unroll
            for (int j = 0; j < 2; ++j)
                bF[j] = *(const bf16x8*)&sB[(wn * 32 + j * 16 + r) * BK + ch];
#pragma unroll
            for (int i = 0; i < 4; ++i)
#pragma unroll
                for (int j = 0; j < 2; ++j)
                    acc[i][j] = __builtin_amdgcn_mfma_f32_16x16x32_bf16(
                        aF[i], bF[j], acc[i][j], 0, 0, 0);
        }
    }

#pragma unroll
    for (int i = 0; i < 4; ++i)
#pragma unroll
        for (int j = 0; j < 2; ++j)
#pragma unroll
            for (int rr = 0; rr < 4; ++rr) {
                const int row = rowA0 + i * 16 + q * 4 + rr;
                const int col = wn * 32 + j * 16 + r;
                Cz[(size_t)row * 128 + col] = acc[i][j][rr];
            }

    // last z-block for this x reduces all 4 partials -> t2buf
    __threadfence();
    __syncthreads();
    if (t == 0) lastz = (atomicAdd(&cnt2[blockIdx.x], 1) == 3);
    __syncthreads();
    if (lastz) {
        const int b = rowA0 >> 9;
        for (int idx = t; idx < 64 * 128; idx += 256) {
            const int row = rowA0 + (idx >> 7);
            const int col = idx & 127;
            const size_t o = (size_t)row * 128 + col;
            float s = 0.f;
#pragma unroll
            for (int z2 = 0; z2 < 4; ++z2)
                s += __hip_atomic_load(&Cpart[(size_t)z2 * 8192 * 128 + o],
                                       __ATOMIC_RELAXED,
                                       __HIP_MEMORY_SCOPE_AGENT);
            t2buf[o] = __float2bfloat16(s * gw[b * 128 + col]);
        }
    }
}

// t[i] = bf16(acc[i] * gw[batch(row)][col])   (M x 128)
__global__ void scale_cvt_kernel(const float* __restrict__ acc,
                                 const float* __restrict__ gw,
                                 bf16* __restrict__ outb)
{
    const int i = blockIdx.x * 256 + threadIdx.x;
    const int col = i & 127;
    const int row = i >> 7;
    outb[i] = __float2bfloat16(acc[i] * gw[(row >> 9) * 128 + col]);
}

// ---------------------------------------------------------------------------
// Fused prep: fp32->bf16 casts + coalesced LDS-tile U transposes + merged
// biases + zeroing of gsum/cnt/cnt2 (4352 floats). One launch.
// ---------------------------------------------------------------------------
__device__ __forceinline__ void cvt_range(const float* src, bf16* dst, int base, int t)
{
    const int i = base * 256 + t;
    const float4 v = ((const float4*)src)[i];
    ((bf16x4*)dst)[i] = (bf16x4){(__bf16)v.x, (__bf16)v.y, (__bf16)v.z, (__bf16)v.w};
}

__device__ __forceinline__ void transpose_tile(const float* U, bf16* UT, int F,
                                               int bx, int by, int t,
                                               float (*sh)[65])
{
    const int f0 = bx * 64, ek0 = by * 64;
#pragma unroll
    for (int i = 0; i < 16; ++i) {
        const int row = i * 4 + (t >> 6);
        const int col = t & 63;
        sh[row][col] = U[(size_t)(ek0 + row) * F + f0 + col];
    }
    __syncthreads();
#pragma unroll
    for (int i = 0; i < 16; ++i) {
        const int row = i * 4 + (t >> 6);
        const int col = t & 63;
        UT[(size_t)(f0 + row) * 128 + ek0 + col] = __float2bfloat16(sh[col][row]);
    }
}

__global__ void prep_all(const float* __restrict__ x,    bf16* __restrict__ xb,
                         const float* __restrict__ W1,   bf16* __restrict__ W1b,
                         const float* __restrict__ W2,   bf16* __restrict__ W2b,
                         const float* __restrict__ gw1,  bf16* __restrict__ gw1b,
                         const float* __restrict__ gw2,  bf16* __restrict__ gw2b,
                         const float* __restrict__ SVH1, bf16* __restrict__ svh1b,
                         const float* __restrict__ SVH2, bf16* __restrict__ svh2b,
                         const float* __restrict__ U1,   bf16* __restrict__ U1T,
                         const float* __restrict__ U2,   bf16* __restrict__ U2T,
                         const float* __restrict__ b1,   const float* __restrict__ TB1,
                         const float* __restrict__ b2,   const float* __restrict__ TB2,
                         float* __restrict__ b1m, float* __restrict__ b2m,
                         float* __restrict__ gsum)
{
    __shared__ float sh[64][65];
    const int b = blockIdx.x;
    const int t = threadIdx.x;
    if      (b < 6144)  cvt_range(x,   xb,   b,         t);
    else if (b < 8448)  cvt_range(W1,  W1b,  b - 6144,  t);
    else if (b < 10752) cvt_range(W2,  W2b,  b - 8448,  t);
    else if (b < 10944) cvt_range(gw1, gw1b, b - 10752, t);
    else if (b < 10976) cvt_range(gw2, gw2b, b - 10944, t);
    else if (b < 11072) cvt_range(SVH1, svh1b, b - 10976, t);
    else if (b < 11456) cvt_range(SVH2, svh2b, b - 11072, t);
    else if (b < 11552) {          // U1 [128,3072] -> U1T: 48 x 2 tiles
        const int b2 = b - 11456;
        transpose_tile(U1, U1T, 3072, b2 >> 1, b2 & 1, t, sh);
    } else if (b < 11576) {        // U2 [128,768] -> U2T: 12 x 2 tiles
        const int b2 = b - 11552;
        transpose_tile(U2, U2T, 768, b2 >> 1, b2 & 1, t, sh);
    } else if (b < 11591) {        // merged biases
        const int i = (b - 11576) * 256 + t;
        if (i < 3072) {
            float s = 0.f;
            for (int e = 0; e < 8; ++e) s += TB1[e * 3072 + i];
            b1m[i] = b1[i] + 0.2f * s;
        } else if (i < 3840) {
            const int j = i - 3072;
            float s = 0.f;
            for (int e = 0; e < 8; ++e) s += TB2[e * 768 + j];
            b2m[j] = b2[j] + 0.2f * s;
        }
    } else {                       // zero gsum[4096] + cnt + cnt2 (4352 f)
        const int i = (b - 11591) * 256 + t;
        gsum[i] = 0.f;
    }
}

// ---------------------------------------------------------------------------
extern "C" void kernel_launch(void* const* d_in, const int* in_sizes, int n_in,
                              void* d_out, int out_size, void* d_ws, size_t ws_size,
                              hipStream_t stream)
{
    const float* x       = (const float*)d_in[0];
    const float* gate_w1 = (const float*)d_in[1];
    const float* gate_b1 = (const float*)d_in[2];
    const float* gate_w2 = (const float*)d_in[3];
    const float* gate_b2 = (const float*)d_in[4];
    const float* W1      = (const float*)d_in[5];
    const float* b1      = (const float*)d_in[6];
    const float* W2      = (const float*)d_in[7];
    const float* b2      = (const float*)d_in[8];
    const float* U1      = (const float*)d_in[9];
    const float* SVH1    = (const float*)d_in[10];
    const float* U2      = (const float*)d_in[11];
    const float* SVH2    = (const float*)d_in[12];
    const float* TB1     = (const float*)d_in[13];
    const float* TB2     = (const float*)d_in[14];
    float* out = (float*)d_out;                     // [8192, 768] fp32

    char* p = (char*)d_ws;
    auto alloc = [&](size_t bytes) {
        char* q = p;
        p += (bytes + 255) & ~(size_t)255;
        return q;
    };
    bf16* hbuf  = (bf16*)alloc((size_t)8192 * 3072 * 2);
    bf16* xb    = (bf16*)alloc((size_t)8192 * 768 * 2);
    bf16* t1buf = (bf16*)alloc((size_t)8192 * 128 * 2);
    bf16* t2buf = (bf16*)alloc((size_t)8192 * 128 * 2);
    bf16* W1b   = (bf16*)alloc((size_t)3072 * 768 * 2);
    bf16* W2b   = (bf16*)alloc((size_t)768 * 3072 * 2);
    // gw1b and svh1b MUST be contiguous: rt1_kernel treats them as one
    // [384, 768] B matrix. 256*768*2 = 393216 B (multiple of 256 -> no pad).
    bf16* gw1b  = (bf16*)alloc((size_t)256 * 768 * 2);
    bf16* svh1b = (bf16*)alloc((size_t)128 * 768 * 2);
    bf16* gw2b  = (bf16*)alloc((size_t)128 * 256 * 2);
    bf16* svh2b = (bf16*)alloc((size_t)128 * 3072 * 2);
    bf16* U1T   = (bf16*)alloc((size_t)3072 * 128 * 2);
    bf16* U2T   = (bf16*)alloc((size_t)768 * 128 * 2);
    float* gsum = (float*)alloc(4352 * 4);   // gsum[4096] + cnt + cnt2[128]
    int*   cnt  = (int*)(gsum + 4096);
    int*   cnt2 = (int*)(gsum + 4097);
    float* gw   = (float*)alloc(2048 * 4);
    float* b1m  = (float*)alloc(3072 * 4);
    float* b2m  = (float*)alloc(768 * 4);
    float* t1acc  = (float*)alloc((size_t)8192 * 128 * 4);
    float* t2part = (float*)alloc((size_t)4 * 8192 * 128 * 4);

    const dim3 blk(256);

    prep_all<<<11608, blk, 0, stream>>>(x, xb, W1, W1b, W2, W2b,
                                        gate_w1, gw1b, gate_w2, gw2b,
                                        SVH1, svh1b, SVH2, svh2b,
                                        U1, U1T, U2, U2T,
                                        b1, TB1, b2, TB2, b1m, b2m,
                                        gsum);

    // fused router + t1raw + gw (64x64 tiles, 768 balanced blocks)
    rt1_kernel<<<dim3(128, 6), blk, 0, stream>>>(xb, 768, gw1b, 768,
                                                 gate_b1, gw2b, gate_b2,
                                                 gsum, cnt, gw, t1acc);
    // t1 = t1acc * gw -> bf16
    scale_cvt_kernel<<<4096, blk, 0, stream>>>(t1acc, gw, t1buf);

    // h = relu([x|t1] @ [W1|U1T]^T + b1m)              [8192, 3072]
    gemm_bt<<<dim3(64, 24), blk, 0, stream>>>(xb, 768, 768, t1buf, 128, 128,
                                              W1b, 768, U1T, 128,
                                              b1m, 1, hbuf, 3072);

    // t2part[z] = h @ SVH2^T slice; last z-block per x fuses reduce+scale
    t2_splitk<<<dim3(128, 1, 4), blk, 0, stream>>>(hbuf, 3072, svh2b, 3072,
                                                   t2part, gw, t2buf, cnt2);

    // out = [h|t2] @ [W2|U2T]^T + b2m  (fp32 out)      [8192, 768]
    gemm_bt64<<<dim3(128, 6), blk, 0, stream>>>(hbuf, 3072, 3072, t2buf, 128, 128,
                                                W2b, 3072, U2T, 128,
                                                b2m, out, 768);
}

// Round 7
// 266.149 us; speedup vs baseline: 1.3951x; 1.3951x over previous
//
#include <hip/hip_runtime.h>
#include <hip/hip_bf16.h>

using bf16 = __hip_bfloat16;
typedef __bf16 bf16x8 __attribute__((ext_vector_type(8)));
typedef __bf16 bf16x4 __attribute__((ext_vector_type(4)));
typedef float f32x4 __attribute__((ext_vector_type(4)));
typedef float f32x16 __attribute__((ext_vector_type(16)));

#define BK 64

// ---------------------------------------------------------------------------
// Staging helper: 16B per lane via global_load_lds, wave-uniform LDS base.
// ---------------------------------------------------------------------------
__device__ __forceinline__ void stage16(const bf16* gsrc, bf16* lds_base)
{
    __builtin_amdgcn_global_load_lds(
        (__attribute__((address_space(1))) void*)(void*)gsrc,
        (__attribute__((address_space(3))) void*)(void*)lds_base,
        16, 0, 0);
}

// History:
// R5: chunk swizzle c^(row&7) killed 16x16-pattern conflicts (1.65e7->0).
// R11: 256^2 8-phase regressed (grid quantization + short K). Wrong regime.
// R12: 32x32x16 MFMA: fc1 67->62.6us; adds 5.5e6 conflict-cyc (4/read).
// R13: conflict is a 32-lane half-wave floor for b128 reads of 32x32
//      frags; row-XOR can't fix. ACCEPTED (~2-5us, partly hidden).
// R14: t2 de-atomicized (split-K partials), rt1 768 blocks. 281->261us.
//      Session clock noise band +-12%: don't chase <10% single-kernel deltas.
// R15: fc2 128^2 retile REGRESSED (384 blocks = 1.5 rounds) — quantization
//      trap. rt1 gw fusion cost ~40us. Total 319. REVERTED.
// R16: t2 last-z-block fused reduce REGRESSED 15->88us: __threadfence
//      (device-scope L2 writeback) x512 blocks + scalar AGENT-scope atomic
//      loads in a 128-block tail = 40-70us per fused kernel. RULE: ad-hoc
//      cross-workgroup producer-consumer inside a kernel costs far more
//      than the ~10us launch it saves. Both fusions REVERTED.
// R17 (this round): exact restoration of the R14 configuration (261.3us
//      verified) — re-anchor the best state.
// ---------------------------------------------------------------------------

// ---------------------------------------------------------------------------
// fc1: 128x128 tiled MFMA GEMM, 32x32x16 fragments.
// C = relu([A0|A1] @ [B0;B1]^T + bias), bf16 out. Block=256 (4 waves, 2x2,
// each wave 64x64 = 2x2 fragments of 32x32).
// C/D: col=lane&31, row=(reg&3)+8*(reg>>2)+4*(lane>>5)  [m74/m101 verified].
// ---------------------------------------------------------------------------
__global__ __launch_bounds__(256)
void gemm_bt(const bf16* __restrict__ A0, int lda0, int K0,
             const bf16* __restrict__ A1, int lda1, int K1,
             const bf16* __restrict__ B0, int ldb0,
             const bf16* __restrict__ B1, int ldb1,
             const float* __restrict__ bias,
             int relu,
             bf16* __restrict__ C, int ldc)
{
    __shared__ bf16 sA[128 * BK];
    __shared__ bf16 sB[128 * BK];

    const int t = threadIdx.x;
    const int w = t >> 6;
    const int l = t & 63;
    const int wm = w >> 1;
    const int wn = w & 1;
    const int r32 = l & 31;        // row within 32x32 fragment
    const int h   = l >> 5;        // k-half selector
    const int rowA0 = blockIdx.x * 128;
    const int rowB0 = blockIdx.y * 128;

    f32x16 acc[2][2];
#pragma unroll
    for (int i = 0; i < 2; ++i)
#pragma unroll
        for (int j = 0; j < 2; ++j)
#pragma unroll
            for (int e = 0; e < 16; ++e)
                acc[i][j][e] = 0.f;

    const int nK = (K0 + K1) >> 6;
    for (int kt = 0; kt < nK; ++kt) {
        const int k0 = kt << 6;
        const bf16 *Ap, *Bp;
        int la, lb, ks;
        if (k0 < K0) { Ap = A0; la = lda0; Bp = B0; lb = ldb0; ks = k0; }
        else         { Ap = A1; la = lda1; Bp = B1; lb = ldb1; ks = k0 - K0; }

        __syncthreads();
#pragma unroll
        for (int it = 0; it < 4; ++it) {
            const int L   = it * 256 + t;
            const int row = L >> 3;
            const int cb  = (L & 7) ^ (row & 7);   // swizzled source chunk
            stage16(Ap + (size_t)(rowA0 + row) * la + ks + cb * 8,
                    sA + (size_t)(it * 256 + (w << 6)) * 8);
            stage16(Bp + (size_t)(rowB0 + row) * lb + ks + cb * 8,
                    sB + (size_t)(it * 256 + (w << 6)) * 8);
        }
        __syncthreads();

#pragma unroll
        for (int s = 0; s < 4; ++s) {              // 4 x K=16 sub-steps
            bf16x8 aF[2], bF[2];
#pragma unroll
            for (int i = 0; i < 2; ++i) {
                const int row = wm * 64 + i * 32 + r32;
                const int c   = (s * 2 + h) ^ (row & 7);
                aF[i] = *(const bf16x8*)&sA[row * BK + c * 8];
            }
#pragma unroll
            for (int j = 0; j < 2; ++j) {
                const int row = wn * 64 + j * 32 + r32;
                const int c   = (s * 2 + h) ^ (row & 7);
                bF[j] = *(const bf16x8*)&sB[row * BK + c * 8];
            }
#pragma unroll
            for (int i = 0; i < 2; ++i)
#pragma unroll
                for (int j = 0; j < 2; ++j)
                    acc[i][j] = __builtin_amdgcn_mfma_f32_32x32x16_bf16(
                        aF[i], bF[j], acc[i][j], 0, 0, 0);
        }
    }

    // C/D layout: col = lane&31, row = (reg&3) + 8*(reg>>2) + 4*h
#pragma unroll
    for (int i = 0; i < 2; ++i)
#pragma unroll
        for (int j = 0; j < 2; ++j) {
            const int col = rowB0 + wn * 64 + j * 32 + r32;
            const float bc = bias ? bias[col] : 0.f;
#pragma unroll
            for (int reg = 0; reg < 16; ++reg) {
                const int row = rowA0 + wm * 64 + i * 32 +
                                (reg & 3) + 8 * (reg >> 2) + 4 * h;
                float v = acc[i][j][reg] + bc;
                if (relu) v = v > 0.f ? v : 0.f;
                C[(size_t)row * ldc + col] = __float2bfloat16(v);
            }
        }
}

// ---------------------------------------------------------------------------
// fc2: 64x128 tile, fp32 out, 32x32x16 fragments. Grid (128,6)=768 blocks
// = 3.0 even rounds. 4 waves 1x4; each wave 64x32 = 2x1 frags of 32x32.
// ---------------------------------------------------------------------------
__global__ __launch_bounds__(256)
void gemm_bt64(const bf16* __restrict__ A0, int lda0, int K0,
               const bf16* __restrict__ A1, int lda1, int K1,
               const bf16* __restrict__ B0, int ldb0,
               const bf16* __restrict__ B1, int ldb1,
               const float* __restrict__ bias,
               float* __restrict__ Cf, int ldc)
{
    __shared__ bf16 sA[64 * BK];
    __shared__ bf16 sB[128 * BK];

    const int t = threadIdx.x;
    const int w = t >> 6;
    const int l = t & 63;
    const int wn = w;
    const int r32 = l & 31;
    const int h   = l >> 5;
    const int rowA0 = blockIdx.x * 64;
    const int rowB0 = blockIdx.y * 128;

    f32x16 acc[2];
#pragma unroll
    for (int i = 0; i < 2; ++i)
#pragma unroll
        for (int e = 0; e < 16; ++e)
            acc[i][e] = 0.f;

    const int nK = (K0 + K1) >> 6;
    for (int kt = 0; kt < nK; ++kt) {
        const int k0 = kt << 6;
        const bf16 *Ap, *Bp;
        int la, lb, ks;
        if (k0 < K0) { Ap = A0; la = lda0; Bp = B0; lb = ldb0; ks = k0; }
        else         { Ap = A1; la = lda1; Bp = B1; lb = ldb1; ks = k0 - K0; }

        __syncthreads();
#pragma unroll
        for (int it = 0; it < 2; ++it) {
            const int L   = it * 256 + t;
            const int row = L >> 3;
            const int cb  = (L & 7) ^ (row & 7);
            stage16(Ap + (size_t)(rowA0 + row) * la + ks + cb * 8,
                    sA + (size_t)(it * 256 + (w << 6)) * 8);
        }
#pragma unroll
        for (int it = 0; it < 4; ++it) {
            const int L   = it * 256 + t;
            const int row = L >> 3;
            const int cb  = (L & 7) ^ (row & 7);
            stage16(Bp + (size_t)(rowB0 + row) * lb + ks + cb * 8,
                    sB + (size_t)(it * 256 + (w << 6)) * 8);
        }
        __syncthreads();

#pragma unroll
        for (int s = 0; s < 4; ++s) {
            bf16x8 aF[2], bF;
#pragma unroll
            for (int i = 0; i < 2; ++i) {
                const int row = i * 32 + r32;
                const int c   = (s * 2 + h) ^ (row & 7);
                aF[i] = *(const bf16x8*)&sA[row * BK + c * 8];
            }
            {
                const int row = wn * 32 + r32;
                const int c   = (s * 2 + h) ^ (row & 7);
                bF = *(const bf16x8*)&sB[row * BK + c * 8];
            }
#pragma unroll
            for (int i = 0; i < 2; ++i)
                acc[i] = __builtin_amdgcn_mfma_f32_32x32x16_bf16(
                    aF[i], bF, acc[i], 0, 0, 0);
        }
    }

#pragma unroll
    for (int i = 0; i < 2; ++i) {
        const int col = rowB0 + wn * 32 + r32;
        const float bc = bias[col];
#pragma unroll
        for (int reg = 0; reg < 16; ++reg) {
            const int row = rowA0 + i * 32 + (reg & 3) + 8 * (reg >> 2) + 4 * h;
            Cf[(size_t)row * ldc + col] = acc[i][reg] + bc;
        }
    }
}

// ---------------------------------------------------------------------------
// Fused router + t1 GEMM, 64x64 tiles. B = [gate_w1 ; SVH1] contiguous
// [384,768]. Grid (128, 6) = 768 blocks = 3.0 even rounds.
//   y=0..3 (router): bias+relu+64-row sum -> atomicAdd gsum[16,256].
//   y=4,5  (t1):     raw fp32 x@SVH1^T -> t1acc (non-atomic).
// 4 waves 2x2; each wave 32x32 = 2x2 frags of 16x16 (R5 swizzle, clean).
// ---------------------------------------------------------------------------
__global__ __launch_bounds__(256)
void rt1_kernel(const bf16* __restrict__ A, int lda,
                const bf16* __restrict__ B, int ldb,
                const float* __restrict__ gate_b1,
                float* __restrict__ gsum, float* __restrict__ t1acc)
{
    __shared__ bf16 sA[64 * BK];
    __shared__ bf16 sB[64 * BK];

    const int t = threadIdx.x;
    const int w = t >> 6;
    const int l = t & 63;
    const int wm = w >> 1;
    const int wn = w & 1;
    const int r = l & 15;
    const int q = l >> 4;
    const int sw = r & 7;
    const int rowA0 = blockIdx.x * 64;
    const int rowB0 = blockIdx.y * 64;
    const int b = rowA0 >> 9;

    f32x4 acc[2][2];
#pragma unroll
    for (int i = 0; i < 2; ++i)
#pragma unroll
        for (int j = 0; j < 2; ++j)
            acc[i][j] = (f32x4){0.f, 0.f, 0.f, 0.f};

    for (int kt = 0; kt < 12; ++kt) {      // K = 768
        const int ks = kt << 6;

        __syncthreads();
#pragma unroll
        for (int it = 0; it < 2; ++it) {
            const int L   = it * 256 + t;
            const int row = L >> 3;
            const int cb  = (L & 7) ^ (row & 7);
            stage16(A + (size_t)(rowA0 + row) * lda + ks + cb * 8,
                    sA + (size_t)(it * 256 + (w << 6)) * 8);
            stage16(B + (size_t)(rowB0 + row) * ldb + ks + cb * 8,
                    sB + (size_t)(it * 256 + (w << 6)) * 8);
        }
        __syncthreads();

#pragma unroll
        for (int kk = 0; kk < 2; ++kk) {
            const int ch = ((kk * 4 + q) ^ sw) * 8;
            bf16x8 aF[2], bF[2];
#pragma unroll
            for (int i = 0; i < 2; ++i)
                aF[i] = *(const bf16x8*)&sA[(wm * 32 + i * 16 + r) * BK + ch];
#pragma unroll
            for (int j = 0; j < 2; ++j)
                bF[j] = *(const bf16x8*)&sB[(wn * 32 + j * 16 + r) * BK + ch];
#pragma unroll
            for (int i = 0; i < 2; ++i)
#pragma unroll
                for (int j = 0; j < 2; ++j)
                    acc[i][j] = __builtin_amdgcn_mfma_f32_16x16x32_bf16(
                        aF[i], bF[j], acc[i][j], 0, 0, 0);
        }
    }

    if (rowB0 < 256) {
        // router: relu + per-wave 32-row sum; waves atomically merge
#pragma unroll
        for (int j = 0; j < 2; ++j) {
            const int col = rowB0 + wn * 32 + j * 16 + r;
            const float bc = gate_b1[col];
            float s = 0.f;
#pragma unroll
            for (int i = 0; i < 2; ++i)
#pragma unroll
                for (int rr = 0; rr < 4; ++rr) {
                    const float v = acc[i][j][rr] + bc;
                    s += v > 0.f ? v : 0.f;
                }
            s += __shfl_xor(s, 16, 64);
            s += __shfl_xor(s, 32, 64);
            if (q == 0) atomicAdd(&gsum[b * 256 + col], s);
        }
    } else {
#pragma unroll
        for (int i = 0; i < 2; ++i)
#pragma unroll
            for (int j = 0; j < 2; ++j)
#pragma unroll
                for (int rr = 0; rr < 4; ++rr) {
                    const int row = rowA0 + wm * 32 + i * 16 + q * 4 + rr;
                    const int col = (rowB0 - 256) + wn * 32 + j * 16 + r;
                    t1acc[(size_t)row * 128 + col] = acc[i][j][rr];
                }
    }
}

// ---------------------------------------------------------------------------
// t2 split-K: grid (128, 1, 4), 64x128 tiles, 12 K-tiles per z, NON-ATOMIC
// per-z partial stores. Cpart layout [4][8192][128] fp32.
// ---------------------------------------------------------------------------
__global__ __launch_bounds__(256)
void t2_splitk(const bf16* __restrict__ A, int lda,
               const bf16* __restrict__ B, int ldb,
               float* __restrict__ Cpart)
{
    __shared__ bf16 sA[64 * BK];
    __shared__ bf16 sB[128 * BK];

    const int t = threadIdx.x;
    const int w = t >> 6;
    const int l = t & 63;
    const int wn = w;
    const int r = l & 15;
    const int q = l >> 4;
    const int sw = r & 7;
    const int rowA0 = blockIdx.x * 64;
    const int z = blockIdx.z;
    const int ksbase = z * 12 * BK;
    float* Cz = Cpart + (size_t)z * 8192 * 128;

    f32x4 acc[4][2];
#pragma unroll
    for (int i = 0; i < 4; ++i)
#pragma unroll
        for (int j = 0; j < 2; ++j)
            acc[i][j] = (f32x4){0.f, 0.f, 0.f, 0.f};

    for (int kt = 0; kt < 12; ++kt) {
        const int ks = ksbase + kt * BK;

        __syncthreads();
#pragma unroll
        for (int it = 0; it < 2; ++it) {
            const int L   = it * 256 + t;
            const int row = L >> 3;
            const int cb  = (L & 7) ^ (row & 7);
            stage16(A + (size_t)(rowA0 + row) * lda + ks + cb * 8,
                    sA + (size_t)(it * 256 + (w << 6)) * 8);
        }
#pragma unroll
        for (int it = 0; it < 4; ++it) {
            const int L   = it * 256 + t;
            const int row = L >> 3;
            const int cb  = (L & 7) ^ (row & 7);
            stage16(B + (size_t)row * ldb + ks + cb * 8,
                    sB + (size_t)(it * 256 + (w << 6)) * 8);
        }
        __syncthreads();

#pragma unroll
        for (int kk = 0; kk < 2; ++kk) {
            const int ch = ((kk * 4 + q) ^ sw) * 8;
            bf16x8 aF[4], bF[2];
#pragma unroll
            for (int i = 0; i < 4; ++i)
                aF[i] = *(const bf16x8*)&sA[(i * 16 + r) * BK + ch];
#pragma unroll
            for (int j = 0; j < 2; ++j)
                bF[j] = *(const bf16x8*)&sB[(wn * 32 + j * 16 + r) * BK + ch];
#pragma unroll
            for (int i = 0; i < 4; ++i)
#pragma unroll
                for (int j = 0; j < 2; ++j)
                    acc[i][j] = __builtin_amdgcn_mfma_f32_16x16x32_bf16(
                        aF[i], bF[j], acc[i][j], 0, 0, 0);
        }
    }

#pragma unroll
    for (int i = 0; i < 4; ++i)
#pragma unroll
        for (int j = 0; j < 2; ++j)
#pragma unroll
            for (int rr = 0; rr < 4; ++rr) {
                const int row = rowA0 + i * 16 + q * 4 + rr;
                const int col = wn * 32 + j * 16 + r;
                Cz[(size_t)row * 128 + col] = acc[i][j][rr];
            }
}

// t[i] = bf16(acc[i] * gw[batch(row)][col])   (M x 128)
__global__ void scale_cvt_kernel(const float* __restrict__ acc,
                                 const float* __restrict__ gw,
                                 bf16* __restrict__ outb)
{
    const int i = blockIdx.x * 256 + threadIdx.x;
    const int col = i & 127;
    const int row = i >> 7;
    outb[i] = __float2bfloat16(acc[i] * gw[(row >> 9) * 128 + col]);
}

// t[i] = bf16((sum_z part[z][i]) * gw[batch(row)][col])   (reduce z=4)
__global__ void scale_red4_cvt(const float* __restrict__ part,
                               const float* __restrict__ gw,
                               bf16* __restrict__ outb)
{
    const int i = blockIdx.x * 256 + threadIdx.x;
    const int col = i & 127;
    const int row = i >> 7;
    const float s = part[i] + part[1048576 + i] +
                    part[2097152 + i] + part[3145728 + i];
    outb[i] = __float2bfloat16(s * gw[(row >> 9) * 128 + col]);
}

// ---------------------------------------------------------------------------
// Fused prep: fp32->bf16 casts + coalesced LDS-tile U transposes + merged
// biases + zeroing of gsum. One launch.
// ---------------------------------------------------------------------------
__device__ __forceinline__ void cvt_range(const float* src, bf16* dst, int base, int t)
{
    const int i = base * 256 + t;
    const float4 v = ((const float4*)src)[i];
    ((bf16x4*)dst)[i] = (bf16x4){(__bf16)v.x, (__bf16)v.y, (__bf16)v.z, (__bf16)v.w};
}

__device__ __forceinline__ void transpose_tile(const float* U, bf16* UT, int F,
                                               int bx, int by, int t,
                                               float (*sh)[65])
{
    const int f0 = bx * 64, ek0 = by * 64;
#pragma unroll
    for (int i = 0; i < 16; ++i) {
        const int row = i * 4 + (t >> 6);
        const int col = t & 63;
        sh[row][col] = U[(size_t)(ek0 + row) * F + f0 + col];
    }
    __syncthreads();
#pragma unroll
    for (int i = 0; i < 16; ++i) {
        const int row = i * 4 + (t >> 6);
        const int col = t & 63;
        UT[(size_t)(f0 + row) * 128 + ek0 + col] = __float2bfloat16(sh[col][row]);
    }
}

__global__ void prep_all(const float* __restrict__ x,    bf16* __restrict__ xb,
                         const float* __restrict__ W1,   bf16* __restrict__ W1b,
                         const float* __restrict__ W2,   bf16* __restrict__ W2b,
                         const float* __restrict__ gw1,  bf16* __restrict__ gw1b,
                         const float* __restrict__ gw2,  bf16* __restrict__ gw2b,
                         const float* __restrict__ SVH1, bf16* __restrict__ svh1b,
                         const float* __restrict__ SVH2, bf16* __restrict__ svh2b,
                         const float* __restrict__ U1,   bf16* __restrict__ U1T,
                         const float* __restrict__ U2,   bf16* __restrict__ U2T,
                         const float* __restrict__ b1,   const float* __restrict__ TB1,
                         const float* __restrict__ b2,   const float* __restrict__ TB2,
                         float* __restrict__ b1m, float* __restrict__ b2m,
                         float* __restrict__ gsum)
{
    __shared__ float sh[64][65];
    const int b = blockIdx.x;
    const int t = threadIdx.x;
    if      (b < 6144)  cvt_range(x,   xb,   b,         t);
    else if (b < 8448)  cvt_range(W1,  W1b,  b - 6144,  t);
    else if (b < 10752) cvt_range(W2,  W2b,  b - 8448,  t);
    else if (b < 10944) cvt_range(gw1, gw1b, b - 10752, t);
    else if (b < 10976) cvt_range(gw2, gw2b, b - 10944, t);
    else if (b < 11072) cvt_range(SVH1, svh1b, b - 10976, t);
    else if (b < 11456) cvt_range(SVH2, svh2b, b - 11072, t);
    else if (b < 11552) {          // U1 [128,3072] -> U1T: 48 x 2 tiles
        const int b2 = b - 11456;
        transpose_tile(U1, U1T, 3072, b2 >> 1, b2 & 1, t, sh);
    } else if (b < 11576) {        // U2 [128,768] -> U2T: 12 x 2 tiles
        const int b2 = b - 11552;
        transpose_tile(U2, U2T, 768, b2 >> 1, b2 & 1, t, sh);
    } else if (b < 11591) {        // merged biases
        const int i = (b - 11576) * 256 + t;
        if (i < 3072) {
            float s = 0.f;
            for (int e = 0; e < 8; ++e) s += TB1[e * 3072 + i];
            b1m[i] = b1[i] + 0.2f * s;
        } else if (i < 3840) {
            const int j = i - 3072;
            float s = 0.f;
            for (int e = 0; e < 8; ++e) s += TB2[e * 768 + j];
            b2m[j] = b2[j] + 0.2f * s;
        }
    } else {                       // zero gsum[4096]
        const int i = (b - 11591) * 256 + t;
        gsum[i] = 0.f;
    }
}

// gw[b,c] = gate_b2[c] + (1/512) * sum_j gsum[b,j] * gate_w2[c,j]
__global__ void gw_kernel(const float* __restrict__ gsum, const bf16* __restrict__ gw2b,
                          const float* __restrict__ gate_b2, float* __restrict__ gw)
{
    const int b = blockIdx.x;
    const int c = threadIdx.x;
    const bf16x8* wrow = (const bf16x8*)&gw2b[c * 256];
    const float* gs = &gsum[b * 256];
    float s = 0.f;
    for (int j8 = 0; j8 < 32; ++j8) {
        const bf16x8 v = wrow[j8];
#pragma unroll
        for (int e = 0; e < 8; ++e)
            s += gs[j8 * 8 + e] * (float)v[e];
    }
    gw[b * 128 + c] = gate_b2[c] + s * (1.0f / 512.0f);
}

// ---------------------------------------------------------------------------
extern "C" void kernel_launch(void* const* d_in, const int* in_sizes, int n_in,
                              void* d_out, int out_size, void* d_ws, size_t ws_size,
                              hipStream_t stream)
{
    const float* x       = (const float*)d_in[0];
    const float* gate_w1 = (const float*)d_in[1];
    const float* gate_b1 = (const float*)d_in[2];
    const float* gate_w2 = (const float*)d_in[3];
    const float* gate_b2 = (const float*)d_in[4];
    const float* W1      = (const float*)d_in[5];
    const float* b1      = (const float*)d_in[6];
    const float* W2      = (const float*)d_in[7];
    const float* b2      = (const float*)d_in[8];
    const float* U1      = (const float*)d_in[9];
    const float* SVH1    = (const float*)d_in[10];
    const float* U2      = (const float*)d_in[11];
    const float* SVH2    = (const float*)d_in[12];
    const float* TB1     = (const float*)d_in[13];
    const float* TB2     = (const float*)d_in[14];
    float* out = (float*)d_out;                     // [8192, 768] fp32

    char* p = (char*)d_ws;
    auto alloc = [&](size_t bytes) {
        char* q = p;
        p += (bytes + 255) & ~(size_t)255;
        return q;
    };
    bf16* hbuf  = (bf16*)alloc((size_t)8192 * 3072 * 2);
    bf16* xb    = (bf16*)alloc((size_t)8192 * 768 * 2);
    bf16* t1buf = (bf16*)alloc((size_t)8192 * 128 * 2);
    bf16* t2buf = (bf16*)alloc((size_t)8192 * 128 * 2);
    bf16* W1b   = (bf16*)alloc((size_t)3072 * 768 * 2);
    bf16* W2b   = (bf16*)alloc((size_t)768 * 3072 * 2);
    // gw1b and svh1b MUST be contiguous: rt1_kernel treats them as one
    // [384, 768] B matrix. 256*768*2 = 393216 B (multiple of 256 -> no pad).
    bf16* gw1b  = (bf16*)alloc((size_t)256 * 768 * 2);
    bf16* svh1b = (bf16*)alloc((size_t)128 * 768 * 2);
    bf16* gw2b  = (bf16*)alloc((size_t)128 * 256 * 2);
    bf16* svh2b = (bf16*)alloc((size_t)128 * 3072 * 2);
    bf16* U1T   = (bf16*)alloc((size_t)3072 * 128 * 2);
    bf16* U2T   = (bf16*)alloc((size_t)768 * 128 * 2);
    float* gsum = (float*)alloc(16 * 256 * 4);
    float* gw   = (float*)alloc(2048 * 4);
    float* b1m  = (float*)alloc(3072 * 4);
    float* b2m  = (float*)alloc(768 * 4);
    float* t1acc  = (float*)alloc((size_t)8192 * 128 * 4);
    float* t2part = (float*)alloc((size_t)4 * 8192 * 128 * 4);

    const dim3 blk(256);

    prep_all<<<11607, blk, 0, stream>>>(x, xb, W1, W1b, W2, W2b,
                                        gate_w1, gw1b, gate_w2, gw2b,
                                        SVH1, svh1b, SVH2, svh2b,
                                        U1, U1T, U2, U2T,
                                        b1, TB1, b2, TB2, b1m, b2m,
                                        gsum);

    // fused router + t1raw (64x64 tiles, 768 balanced blocks)
    rt1_kernel<<<dim3(128, 6), blk, 0, stream>>>(xb, 768, gw1b, 768,
                                                 gate_b1, gsum, t1acc);
    // gw = gsum/512 @ gate_w2^T + gate_b2              [16, 128]
    gw_kernel<<<16, 128, 0, stream>>>(gsum, gw2b, gate_b2, gw);
    // t1 = t1acc * gw -> bf16
    scale_cvt_kernel<<<4096, blk, 0, stream>>>(t1acc, gw, t1buf);

    // h = relu([x|t1] @ [W1|U1T]^T + b1m)              [8192, 3072]
    gemm_bt<<<dim3(64, 24), blk, 0, stream>>>(xb, 768, 768, t1buf, 128, 128,
                                              W1b, 768, U1T, 128,
                                              b1m, 1, hbuf, 3072);

    // t2part[z] = h @ SVH2^T slice (split-K z=4, non-atomic) [4][8192, 128]
    t2_splitk<<<dim3(128, 1, 4), blk, 0, stream>>>(hbuf, 3072, svh2b, 3072, t2part);
    // t2 = (sum_z t2part[z]) * gw -> bf16
    scale_red4_cvt<<<4096, blk, 0, stream>>>(t2part, gw, t2buf);

    // out = [h|t2] @ [W2|U2T]^T + b2m  (fp32 out)      [8192, 768]
    gemm_bt64<<<dim3(128, 6), blk, 0, stream>>>(hbuf, 3072, 3072, t2buf, 128, 128,
                                                W2b, 3072, U2T, 128,
                                                b2m, out, 768);
}

// Round 8
// 264.952 us; speedup vs baseline: 1.4014x; 1.0045x over previous
//
#include <hip/hip_runtime.h>
#include <hip/hip_bf16.h>

using bf16 = __hip_bfloat16;
typedef __bf16 bf16x8 __attribute__((ext_vector_type(8)));
typedef __bf16 bf16x4 __attribute__((ext_vector_type(4)));
typedef float f32x4 __attribute__((ext_vector_type(4)));
typedef float f32x16 __attribute__((ext_vector_type(16)));

#define BK 64

// ---------------------------------------------------------------------------
// Staging helper: 16B per lane via global_load_lds, wave-uniform LDS base.
// ---------------------------------------------------------------------------
__device__ __forceinline__ void stage16(const bf16* gsrc, bf16* lds_base)
{
    __builtin_amdgcn_global_load_lds(
        (__attribute__((address_space(1))) void*)(void*)gsrc,
        (__attribute__((address_space(3))) void*)(void*)lds_base,
        16, 0, 0);
}

// History:
// R5: chunk swizzle c^(row&7) killed 16x16-pattern conflicts (1.65e7->0).
// R11: 256^2 8-phase regressed (grid quantization + short K). Wrong regime.
// R12: 32x32x16 MFMA: fc1 67->62.6us; adds 5.5e6 conflict-cyc (4/read).
// R13: conflict is a 32-lane half-wave floor for b128 reads of 32x32
//      frags; row-XOR can't fix. ACCEPTED (~2-5us, partly hidden).
// R14: t2 de-atomicized (split-K partials), rt1 768 blocks. 281->261us.
//      Session clock noise band +-12%: don't chase <10% single-kernel deltas.
// R15: fc2 128^2 retile REGRESSED (384 blocks = 1.5 rounds) — quantization
//      trap. rt1 gw fusion cost ~40us. Total 319. REVERTED.
// R16: t2 last-z-block fused reduce REGRESSED 15->88us: cross-workgroup
//      producer-consumer (threadfence + AGENT-scope loads) costs 40-70us
//      per use — far more than the ~10us launch it saves. REVERTED.
// R17: R14 restored, 266.1us — anchor confirmed (total noise ±2%).
// R18 (this round): fc2 retiled 64x128 -> 128x96, grid (64,8)=512 blocks
//      = 2.0 EVEN rounds. L2->LDS staging traffic 931 -> 718 MB (-23%);
//      per-output staging factor 0.0234 -> 0.0182. fc1 at 740 TF ~= 85%
//      of the m97-structure ceiling with short-K discount: DONE.
// ---------------------------------------------------------------------------

// ---------------------------------------------------------------------------
// fc1: 128x128 tiled MFMA GEMM, 32x32x16 fragments.
// C = relu([A0|A1] @ [B0;B1]^T + bias), bf16 out. Block=256 (4 waves, 2x2,
// each wave 64x64 = 2x2 fragments of 32x32).
// C/D: col=lane&31, row=(reg&3)+8*(reg>>2)+4*(lane>>5)  [m74/m101 verified].
// ---------------------------------------------------------------------------
__global__ __launch_bounds__(256)
void gemm_bt(const bf16* __restrict__ A0, int lda0, int K0,
             const bf16* __restrict__ A1, int lda1, int K1,
             const bf16* __restrict__ B0, int ldb0,
             const bf16* __restrict__ B1, int ldb1,
             const float* __restrict__ bias,
             int relu,
             bf16* __restrict__ C, int ldc)
{
    __shared__ bf16 sA[128 * BK];
    __shared__ bf16 sB[128 * BK];

    const int t = threadIdx.x;
    const int w = t >> 6;
    const int l = t & 63;
    const int wm = w >> 1;
    const int wn = w & 1;
    const int r32 = l & 31;        // row within 32x32 fragment
    const int h   = l >> 5;        // k-half selector
    const int rowA0 = blockIdx.x * 128;
    const int rowB0 = blockIdx.y * 128;

    f32x16 acc[2][2];
#pragma unroll
    for (int i = 0; i < 2; ++i)
#pragma unroll
        for (int j = 0; j < 2; ++j)
#pragma unroll
            for (int e = 0; e < 16; ++e)
                acc[i][j][e] = 0.f;

    const int nK = (K0 + K1) >> 6;
    for (int kt = 0; kt < nK; ++kt) {
        const int k0 = kt << 6;
        const bf16 *Ap, *Bp;
        int la, lb, ks;
        if (k0 < K0) { Ap = A0; la = lda0; Bp = B0; lb = ldb0; ks = k0; }
        else         { Ap = A1; la = lda1; Bp = B1; lb = ldb1; ks = k0 - K0; }

        __syncthreads();
#pragma unroll
        for (int it = 0; it < 4; ++it) {
            const int L   = it * 256 + t;
            const int row = L >> 3;
            const int cb  = (L & 7) ^ (row & 7);   // swizzled source chunk
            stage16(Ap + (size_t)(rowA0 + row) * la + ks + cb * 8,
                    sA + (size_t)(it * 256 + (w << 6)) * 8);
            stage16(Bp + (size_t)(rowB0 + row) * lb + ks + cb * 8,
                    sB + (size_t)(it * 256 + (w << 6)) * 8);
        }
        __syncthreads();

#pragma unroll
        for (int s = 0; s < 4; ++s) {              // 4 x K=16 sub-steps
            bf16x8 aF[2], bF[2];
#pragma unroll
            for (int i = 0; i < 2; ++i) {
                const int row = wm * 64 + i * 32 + r32;
                const int c   = (s * 2 + h) ^ (row & 7);
                aF[i] = *(const bf16x8*)&sA[row * BK + c * 8];
            }
#pragma unroll
            for (int j = 0; j < 2; ++j) {
                const int row = wn * 64 + j * 32 + r32;
                const int c   = (s * 2 + h) ^ (row & 7);
                bF[j] = *(const bf16x8*)&sB[row * BK + c * 8];
            }
#pragma unroll
            for (int i = 0; i < 2; ++i)
#pragma unroll
                for (int j = 0; j < 2; ++j)
                    acc[i][j] = __builtin_amdgcn_mfma_f32_32x32x16_bf16(
                        aF[i], bF[j], acc[i][j], 0, 0, 0);
        }
    }

    // C/D layout: col = lane&31, row = (reg&3) + 8*(reg>>2) + 4*h
#pragma unroll
    for (int i = 0; i < 2; ++i)
#pragma unroll
        for (int j = 0; j < 2; ++j) {
            const int col = rowB0 + wn * 64 + j * 32 + r32;
            const float bc = bias ? bias[col] : 0.f;
#pragma unroll
            for (int reg = 0; reg < 16; ++reg) {
                const int row = rowA0 + wm * 64 + i * 32 +
                                (reg & 3) + 8 * (reg >> 2) + 4 * h;
                float v = acc[i][j][reg] + bc;
                if (relu) v = v > 0.f ? v : 0.f;
                C[(size_t)row * ldc + col] = __float2bfloat16(v);
            }
        }
}

// ---------------------------------------------------------------------------
// fc2: 128x96 tile, fp32 out, 32x32x16 fragments (R18). Grid (64,8)=512
// blocks = 2.0 even rounds. 4 waves, each 32 rows x 96 cols = 3 frags.
// Staging: A 128 rows (4 its) + B 96 rows (3 its) = 7 units/thread.
// ---------------------------------------------------------------------------
__global__ __launch_bounds__(256)
void gemm_bt96(const bf16* __restrict__ A0, int lda0, int K0,
               const bf16* __restrict__ A1, int lda1, int K1,
               const bf16* __restrict__ B0, int ldb0,
               const bf16* __restrict__ B1, int ldb1,
               const float* __restrict__ bias,
               float* __restrict__ Cf, int ldc)
{
    __shared__ bf16 sA[128 * BK];
    __shared__ bf16 sB[96 * BK];

    const int t = threadIdx.x;
    const int w = t >> 6;          // wave 0..3 -> rows w*32
    const int l = t & 63;
    const int r32 = l & 31;
    const int h   = l >> 5;
    const int rowA0 = blockIdx.x * 128;
    const int rowB0 = blockIdx.y * 96;

    f32x16 acc[3];
#pragma unroll
    for (int j = 0; j < 3; ++j)
#pragma unroll
        for (int e = 0; e < 16; ++e)
            acc[j][e] = 0.f;

    const int nK = (K0 + K1) >> 6;
    for (int kt = 0; kt < nK; ++kt) {
        const int k0 = kt << 6;
        const bf16 *Ap, *Bp;
        int la, lb, ks;
        if (k0 < K0) { Ap = A0; la = lda0; Bp = B0; lb = ldb0; ks = k0; }
        else         { Ap = A1; la = lda1; Bp = B1; lb = ldb1; ks = k0 - K0; }

        __syncthreads();
#pragma unroll
        for (int it = 0; it < 4; ++it) {           // A: 128 rows
            const int L   = it * 256 + t;
            const int row = L >> 3;
            const int cb  = (L & 7) ^ (row & 7);
            stage16(Ap + (size_t)(rowA0 + row) * la + ks + cb * 8,
                    sA + (size_t)(it * 256 + (w << 6)) * 8);
        }
#pragma unroll
        for (int it = 0; it < 3; ++it) {           // B: 96 rows
            const int L   = it * 256 + t;
            const int row = L >> 3;
            const int cb  = (L & 7) ^ (row & 7);
            stage16(Bp + (size_t)(rowB0 + row) * lb + ks + cb * 8,
                    sB + (size_t)(it * 256 + (w << 6)) * 8);
        }
        __syncthreads();

#pragma unroll
        for (int s = 0; s < 4; ++s) {
            bf16x8 aF, bF[3];
            {
                const int row = w * 32 + r32;
                const int c   = (s * 2 + h) ^ (row & 7);
                aF = *(const bf16x8*)&sA[row * BK + c * 8];
            }
#pragma unroll
            for (int j = 0; j < 3; ++j) {
                const int row = j * 32 + r32;
                const int c   = (s * 2 + h) ^ (row & 7);
                bF[j] = *(const bf16x8*)&sB[row * BK + c * 8];
            }
#pragma unroll
            for (int j = 0; j < 3; ++j)
                acc[j] = __builtin_amdgcn_mfma_f32_32x32x16_bf16(
                    aF, bF[j], acc[j], 0, 0, 0);
        }
    }

#pragma unroll
    for (int j = 0; j < 3; ++j) {
        const int col = rowB0 + j * 32 + r32;
        const float bc = bias[col];
#pragma unroll
        for (int reg = 0; reg < 16; ++reg) {
            const int row = rowA0 + w * 32 + (reg & 3) + 8 * (reg >> 2) + 4 * h;
            Cf[(size_t)row * ldc + col] = acc[j][reg] + bc;
        }
    }
}

// ---------------------------------------------------------------------------
// Fused router + t1 GEMM, 64x64 tiles. B = [gate_w1 ; SVH1] contiguous
// [384,768]. Grid (128, 6) = 768 blocks = 3.0 even rounds.
//   y=0..3 (router): bias+relu+64-row sum -> atomicAdd gsum[16,256].
//   y=4,5  (t1):     raw fp32 x@SVH1^T -> t1acc (non-atomic).
// 4 waves 2x2; each wave 32x32 = 2x2 frags of 16x16 (R5 swizzle, clean).
// ---------------------------------------------------------------------------
__global__ __launch_bounds__(256)
void rt1_kernel(const bf16* __restrict__ A, int lda,
                const bf16* __restrict__ B, int ldb,
                const float* __restrict__ gate_b1,
                float* __restrict__ gsum, float* __restrict__ t1acc)
{
    __shared__ bf16 sA[64 * BK];
    __shared__ bf16 sB[64 * BK];

    const int t = threadIdx.x;
    const int w = t >> 6;
    const int l = t & 63;
    const int wm = w >> 1;
    const int wn = w & 1;
    const int r = l & 15;
    const int q = l >> 4;
    const int sw = r & 7;
    const int rowA0 = blockIdx.x * 64;
    const int rowB0 = blockIdx.y * 64;
    const int b = rowA0 >> 9;

    f32x4 acc[2][2];
#pragma unroll
    for (int i = 0; i < 2; ++i)
#pragma unroll
        for (int j = 0; j < 2; ++j)
            acc[i][j] = (f32x4){0.f, 0.f, 0.f, 0.f};

    for (int kt = 0; kt < 12; ++kt) {      // K = 768
        const int ks = kt << 6;

        __syncthreads();
#pragma unroll
        for (int it = 0; it < 2; ++it) {
            const int L   = it * 256 + t;
            const int row = L >> 3;
            const int cb  = (L & 7) ^ (row & 7);
            stage16(A + (size_t)(rowA0 + row) * lda + ks + cb * 8,
                    sA + (size_t)(it * 256 + (w << 6)) * 8);
            stage16(B + (size_t)(rowB0 + row) * ldb + ks + cb * 8,
                    sB + (size_t)(it * 256 + (w << 6)) * 8);
        }
        __syncthreads();

#pragma unroll
        for (int kk = 0; kk < 2; ++kk) {
            const int ch = ((kk * 4 + q) ^ sw) * 8;
            bf16x8 aF[2], bF[2];
#pragma unroll
            for (int i = 0; i < 2; ++i)
                aF[i] = *(const bf16x8*)&sA[(wm * 32 + i * 16 + r) * BK + ch];
#pragma unroll
            for (int j = 0; j < 2; ++j)
                bF[j] = *(const bf16x8*)&sB[(wn * 32 + j * 16 + r) * BK + ch];
#pragma unroll
            for (int i = 0; i < 2; ++i)
#pragma unroll
                for (int j = 0; j < 2; ++j)
                    acc[i][j] = __builtin_amdgcn_mfma_f32_16x16x32_bf16(
                        aF[i], bF[j], acc[i][j], 0, 0, 0);
        }
    }

    if (rowB0 < 256) {
        // router: relu + per-wave 32-row sum; waves atomically merge
#pragma unroll
        for (int j = 0; j < 2; ++j) {
            const int col = rowB0 + wn * 32 + j * 16 + r;
            const float bc = gate_b1[col];
            float s = 0.f;
#pragma unroll
            for (int i = 0; i < 2; ++i)
#pragma unroll
                for (int rr = 0; rr < 4; ++rr) {
                    const float v = acc[i][j][rr] + bc;
                    s += v > 0.f ? v : 0.f;
                }
            s += __shfl_xor(s, 16, 64);
            s += __shfl_xor(s, 32, 64);
            if (q == 0) atomicAdd(&gsum[b * 256 + col], s);
        }
    } else {
#pragma unroll
        for (int i = 0; i < 2; ++i)
#pragma unroll
            for (int j = 0; j < 2; ++j)
#pragma unroll
                for (int rr = 0; rr < 4; ++rr) {
                    const int row = rowA0 + wm * 32 + i * 16 + q * 4 + rr;
                    const int col = (rowB0 - 256) + wn * 32 + j * 16 + r;
                    t1acc[(size_t)row * 128 + col] = acc[i][j][rr];
                }
    }
}

// ---------------------------------------------------------------------------
// t2 split-K: grid (128, 1, 4), 64x128 tiles, 12 K-tiles per z, NON-ATOMIC
// per-z partial stores. Cpart layout [4][8192][128] fp32.
// ---------------------------------------------------------------------------
__global__ __launch_bounds__(256)
void t2_splitk(const bf16* __restrict__ A, int lda,
               const bf16* __restrict__ B, int ldb,
               float* __restrict__ Cpart)
{
    __shared__ bf16 sA[64 * BK];
    __shared__ bf16 sB[128 * BK];

    const int t = threadIdx.x;
    const int w = t >> 6;
    const int l = t & 63;
    const int wn = w;
    const int r = l & 15;
    const int q = l >> 4;
    const int sw = r & 7;
    const int rowA0 = blockIdx.x * 64;
    const int z = blockIdx.z;
    const int ksbase = z * 12 * BK;
    float* Cz = Cpart + (size_t)z * 8192 * 128;

    f32x4 acc[4][2];
#pragma unroll
    for (int i = 0; i < 4; ++i)
#pragma unroll
        for (int j = 0; j < 2; ++j)
            acc[i][j] = (f32x4){0.f, 0.f, 0.f, 0.f};

    for (int kt = 0; kt < 12; ++kt) {
        const int ks = ksbase + kt * BK;

        __syncthreads();
#pragma unroll
        for (int it = 0; it < 2; ++it) {
            const int L   = it * 256 + t;
            const int row = L >> 3;
            const int cb  = (L & 7) ^ (row & 7);
            stage16(A + (size_t)(rowA0 + row) * lda + ks + cb * 8,
                    sA + (size_t)(it * 256 + (w << 6)) * 8);
        }
#pragma unroll
        for (int it = 0; it < 4; ++it) {
            const int L   = it * 256 + t;
            const int row = L >> 3;
            const int cb  = (L & 7) ^ (row & 7);
            stage16(B + (size_t)row * ldb + ks + cb * 8,
                    sB + (size_t)(it * 256 + (w << 6)) * 8);
        }
        __syncthreads();

#pragma unroll
        for (int kk = 0; kk < 2; ++kk) {
            const int ch = ((kk * 4 + q) ^ sw) * 8;
            bf16x8 aF[4], bF[2];
#pragma unroll
            for (int i = 0; i < 4; ++i)
                aF[i] = *(const bf16x8*)&sA[(i * 16 + r) * BK + ch];
#pragma unroll
            for (int j = 0; j < 2; ++j)
                bF[j] = *(const bf16x8*)&sB[(wn * 32 + j * 16 + r) * BK + ch];
#pragma unroll
            for (int i = 0; i < 4; ++i)
#pragma unroll
                for (int j = 0; j < 2; ++j)
                    acc[i][j] = __builtin_amdgcn_mfma_f32_16x16x32_bf16(
                        aF[i], bF[j], acc[i][j], 0, 0, 0);
        }
    }

#pragma unroll
    for (int i = 0; i < 4; ++i)
#pragma unroll
        for (int j = 0; j < 2; ++j)
#pragma unroll
            for (int rr = 0; rr < 4; ++rr) {
                const int row = rowA0 + i * 16 + q * 4 + rr;
                const int col = wn * 32 + j * 16 + r;
                Cz[(size_t)row * 128 + col] = acc[i][j][rr];
            }
}

// t[i] = bf16(acc[i] * gw[batch(row)][col])   (M x 128)
__global__ void scale_cvt_kernel(const float* __restrict__ acc,
                                 const float* __restrict__ gw,
                                 bf16* __restrict__ outb)
{
    const int i = blockIdx.x * 256 + threadIdx.x;
    const int col = i & 127;
    const int row = i >> 7;
    outb[i] = __float2bfloat16(acc[i] * gw[(row >> 9) * 128 + col]);
}

// t[i] = bf16((sum_z part[z][i]) * gw[batch(row)][col])   (reduce z=4)
__global__ void scale_red4_cvt(const float* __restrict__ part,
                               const float* __restrict__ gw,
                               bf16* __restrict__ outb)
{
    const int i = blockIdx.x * 256 + threadIdx.x;
    const int col = i & 127;
    const int row = i >> 7;
    const float s = part[i] + part[1048576 + i] +
                    part[2097152 + i] + part[3145728 + i];
    outb[i] = __float2bfloat16(s * gw[(row >> 9) * 128 + col]);
}

// ---------------------------------------------------------------------------
// Fused prep: fp32->bf16 casts + coalesced LDS-tile U transposes + merged
// biases + zeroing of gsum. One launch.
// ---------------------------------------------------------------------------
__device__ __forceinline__ void cvt_range(const float* src, bf16* dst, int base, int t)
{
    const int i = base * 256 + t;
    const float4 v = ((const float4*)src)[i];
    ((bf16x4*)dst)[i] = (bf16x4){(__bf16)v.x, (__bf16)v.y, (__bf16)v.z, (__bf16)v.w};
}

__device__ __forceinline__ void transpose_tile(const float* U, bf16* UT, int F,
                                               int bx, int by, int t,
                                               float (*sh)[65])
{
    const int f0 = bx * 64, ek0 = by * 64;
#pragma unroll
    for (int i = 0; i < 16; ++i) {
        const int row = i * 4 + (t >> 6);
        const int col = t & 63;
        sh[row][col] = U[(size_t)(ek0 + row) * F + f0 + col];
    }
    __syncthreads();
#pragma unroll
    for (int i = 0; i < 16; ++i) {
        const int row = i * 4 + (t >> 6);
        const int col = t & 63;
        UT[(size_t)(f0 + row) * 128 + ek0 + col] = __float2bfloat16(sh[col][row]);
    }
}

__global__ void prep_all(const float* __restrict__ x,    bf16* __restrict__ xb,
                         const float* __restrict__ W1,   bf16* __restrict__ W1b,
                         const float* __restrict__ W2,   bf16* __restrict__ W2b,
                         const float* __restrict__ gw1,  bf16* __restrict__ gw1b,
                         const float* __restrict__ gw2,  bf16* __restrict__ gw2b,
                         const float* __restrict__ SVH1, bf16* __restrict__ svh1b,
                         const float* __restrict__ SVH2, bf16* __restrict__ svh2b,
                         const float* __restrict__ U1,   bf16* __restrict__ U1T,
                         const float* __restrict__ U2,   bf16* __restrict__ U2T,
                         const float* __restrict__ b1,   const float* __restrict__ TB1,
                         const float* __restrict__ b2,   const float* __restrict__ TB2,
                         float* __restrict__ b1m, float* __restrict__ b2m,
                         float* __restrict__ gsum)
{
    __shared__ float sh[64][65];
    const int b = blockIdx.x;
    const int t = threadIdx.x;
    if      (b < 6144)  cvt_range(x,   xb,   b,         t);
    else if (b < 8448)  cvt_range(W1,  W1b,  b - 6144,  t);
    else if (b < 10752) cvt_range(W2,  W2b,  b - 8448,  t);
    else if (b < 10944) cvt_range(gw1, gw1b, b - 10752, t);
    else if (b < 10976) cvt_range(gw2, gw2b, b - 10944, t);
    else if (b < 11072) cvt_range(SVH1, svh1b, b - 10976, t);
    else if (b < 11456) cvt_range(SVH2, svh2b, b - 11072, t);
    else if (b < 11552) {          // U1 [128,3072] -> U1T: 48 x 2 tiles
        const int b2 = b - 11456;
        transpose_tile(U1, U1T, 3072, b2 >> 1, b2 & 1, t, sh);
    } else if (b < 11576) {        // U2 [128,768] -> U2T: 12 x 2 tiles
        const int b2 = b - 11552;
        transpose_tile(U2, U2T, 768, b2 >> 1, b2 & 1, t, sh);
    } else if (b < 11591) {        // merged biases
        const int i = (b - 11576) * 256 + t;
        if (i < 3072) {
            float s = 0.f;
            for (int e = 0; e < 8; ++e) s += TB1[e * 3072 + i];
            b1m[i] = b1[i] + 0.2f * s;
        } else if (i < 3840) {
            const int j = i - 3072;
            float s = 0.f;
            for (int e = 0; e < 8; ++e) s += TB2[e * 768 + j];
            b2m[j] = b2[j] + 0.2f * s;
        }
    } else {                       // zero gsum[4096]
        const int i = (b - 11591) * 256 + t;
        gsum[i] = 0.f;
    }
}

// gw[b,c] = gate_b2[c] + (1/512) * sum_j gsum[b,j] * gate_w2[c,j]
__global__ void gw_kernel(const float* __restrict__ gsum, const bf16* __restrict__ gw2b,
                          const float* __restrict__ gate_b2, float* __restrict__ gw)
{
    const int b = blockIdx.x;
    const int c = threadIdx.x;
    const bf16x8* wrow = (const bf16x8*)&gw2b[c * 256];
    const float* gs = &gsum[b * 256];
    float s = 0.f;
    for (int j8 = 0; j8 < 32; ++j8) {
        const bf16x8 v = wrow[j8];
#pragma unroll
        for (int e = 0; e < 8; ++e)
            s += gs[j8 * 8 + e] * (float)v[e];
    }
    gw[b * 128 + c] = gate_b2[c] + s * (1.0f / 512.0f);
}

// ---------------------------------------------------------------------------
extern "C" void kernel_launch(void* const* d_in, const int* in_sizes, int n_in,
                              void* d_out, int out_size, void* d_ws, size_t ws_size,
                              hipStream_t stream)
{
    const float* x       = (const float*)d_in[0];
    const float* gate_w1 = (const float*)d_in[1];
    const float* gate_b1 = (const float*)d_in[2];
    const float* gate_w2 = (const float*)d_in[3];
    const float* gate_b2 = (const float*)d_in[4];
    const float* W1      = (const float*)d_in[5];
    const float* b1      = (const float*)d_in[6];
    const float* W2      = (const float*)d_in[7];
    const float* b2      = (const float*)d_in[8];
    const float* U1      = (const float*)d_in[9];
    const float* SVH1    = (const float*)d_in[10];
    const float* U2      = (const float*)d_in[11];
    const float* SVH2    = (const float*)d_in[12];
    const float* TB1     = (const float*)d_in[13];
    const float* TB2     = (const float*)d_in[14];
    float* out = (float*)d_out;                     // [8192, 768] fp32

    char* p = (char*)d_ws;
    auto alloc = [&](size_t bytes) {
        char* q = p;
        p += (bytes + 255) & ~(size_t)255;
        return q;
    };
    bf16* hbuf  = (bf16*)alloc((size_t)8192 * 3072 * 2);
    bf16* xb    = (bf16*)alloc((size_t)8192 * 768 * 2);
    bf16* t1buf = (bf16*)alloc((size_t)8192 * 128 * 2);
    bf16* t2buf = (bf16*)alloc((size_t)8192 * 128 * 2);
    bf16* W1b   = (bf16*)alloc((size_t)3072 * 768 * 2);
    bf16* W2b   = (bf16*)alloc((size_t)768 * 3072 * 2);
    // gw1b and svh1b MUST be contiguous: rt1_kernel treats them as one
    // [384, 768] B matrix. 256*768*2 = 393216 B (multiple of 256 -> no pad).
    bf16* gw1b  = (bf16*)alloc((size_t)256 * 768 * 2);
    bf16* svh1b = (bf16*)alloc((size_t)128 * 768 * 2);
    bf16* gw2b  = (bf16*)alloc((size_t)128 * 256 * 2);
    bf16* svh2b = (bf16*)alloc((size_t)128 * 3072 * 2);
    bf16* U1T   = (bf16*)alloc((size_t)3072 * 128 * 2);
    bf16* U2T   = (bf16*)alloc((size_t)768 * 128 * 2);
    float* gsum = (float*)alloc(16 * 256 * 4);
    float* gw   = (float*)alloc(2048 * 4);
    float* b1m  = (float*)alloc(3072 * 4);
    float* b2m  = (float*)alloc(768 * 4);
    float* t1acc  = (float*)alloc((size_t)8192 * 128 * 4);
    float* t2part = (float*)alloc((size_t)4 * 8192 * 128 * 4);

    const dim3 blk(256);

    prep_all<<<11607, blk, 0, stream>>>(x, xb, W1, W1b, W2, W2b,
                                        gate_w1, gw1b, gate_w2, gw2b,
                                        SVH1, svh1b, SVH2, svh2b,
                                        U1, U1T, U2, U2T,
                                        b1, TB1, b2, TB2, b1m, b2m,
                                        gsum);

    // fused router + t1raw (64x64 tiles, 768 balanced blocks)
    rt1_kernel<<<dim3(128, 6), blk, 0, stream>>>(xb, 768, gw1b, 768,
                                                 gate_b1, gsum, t1acc);
    // gw = gsum/512 @ gate_w2^T + gate_b2              [16, 128]
    gw_kernel<<<16, 128, 0, stream>>>(gsum, gw2b, gate_b2, gw);
    // t1 = t1acc * gw -> bf16
    scale_cvt_kernel<<<4096, blk, 0, stream>>>(t1acc, gw, t1buf);

    // h = relu([x|t1] @ [W1|U1T]^T + b1m)              [8192, 3072]
    gemm_bt<<<dim3(64, 24), blk, 0, stream>>>(xb, 768, 768, t1buf, 128, 128,
                                              W1b, 768, U1T, 128,
                                              b1m, 1, hbuf, 3072);

    // t2part[z] = h @ SVH2^T slice (split-K z=4, non-atomic) [4][8192, 128]
    t2_splitk<<<dim3(128, 1, 4), blk, 0, stream>>>(hbuf, 3072, svh2b, 3072, t2part);
    // t2 = (sum_z t2part[z]) * gw -> bf16
    scale_red4_cvt<<<4096, blk, 0, stream>>>(t2part, gw, t2buf);

    // out = [h|t2] @ [W2|U2T]^T + b2m  (fp32 out, 128x96 tiles) [8192, 768]
    gemm_bt96<<<dim3(64, 8), blk, 0, stream>>>(hbuf, 3072, 3072, t2buf, 128, 128,
                                               W2b, 3072, U2T, 128,
                                               b2m, out, 768);
}